// Round 10
// baseline (169.878 us; speedup 1.0000x reference)
//
#include <hip/hip_runtime.h>
#include <hip/hip_bf16.h>
#include <math.h>

// Problem constants
#define BATCH 8192
#define NPTS  51              // nb_steps=50 -> 51 quadrature points
#define MTOT  (BATCH*NPTS)    // 417792 = 128 * 3264

typedef __bf16 bf16x8 __attribute__((ext_vector_type(8)));
typedef float  f32x4  __attribute__((ext_vector_type(4)));

// ---- workspace layout (bytes) ----
#define OFF_IW2P  0            // 65536 ushort: iw2 bf16, CHUNK-MAJOR per col-half:
                               //   iw2p[h*32768 + c*1024 + n*8 + j] = bf16(iw2[(h*128+n)*256 + c*8 + j])
#define OFF_W1XB  131072       // 256 ushort bf16 (iw1[:,0])
#define OFF_CC    131584       // 64 f32
#define OFF_STEPS 131840       // 64 f32
#define OFF_OFFS  132096       // 8192 f32
#define OFF_SCAL  164864       // 8192 f32
#define OFF_G1B   197632       // 8192*256 ushort bf16 (h-part of layer1 + ib1, NO relu)
#define OFF_FVALS 4391936      // 417792 f32 (elu(s)+1)*cc, per quadrature point

__device__ __forceinline__ unsigned short f2bf(float f) {
    union { float f; unsigned u; } v; v.f = f;
    unsigned r = v.u + 0x7FFFu + ((v.u >> 16) & 1u);   // RTNE
    return (unsigned short)(r >> 16);
}

__device__ __forceinline__ unsigned pk2bf(float lo, float hi) {
    __hip_bfloat162 t = __float22bfloat162_rn(float2{lo, hi});
    union { __hip_bfloat162 b; unsigned u; } v; v.b = t;
    return v.u;
}

// ---------------- K1: fused prep + second network ----------------
__global__ void k1_fused(const float* __restrict__ iw2, const float* __restrict__ nw1,
                         const float* __restrict__ iw1, const float* __restrict__ ib1,
                         const float* __restrict__ nb1, const float* __restrict__ h,
                         const float* __restrict__ nw2, const float* __restrict__ nb2,
                         const float* __restrict__ nw3, const float* __restrict__ nb3,
                         unsigned short* iw2p, unsigned short* w1xb, float* cc, float* steps,
                         unsigned short* __restrict__ g1b, float* __restrict__ offs,
                         float* __restrict__ scal) {
    int blk = blockIdx.x, tid = threadIdx.x;
    if (blk < 256) {
        int t = blk * 256 + tid;           // t = n*256 + k
        int n = t >> 8, k = t & 255;
        int half = n >> 7, nl = n & 127, c = k >> 3, j = k & 7;
        iw2p[half * 32768 + c * 1024 + nl * 8 + j] = f2bf(iw2[t]);
    } else if (blk == 256) {
        w1xb[tid] = f2bf(iw1[tid * 16]);   // column 0 of iw1, bf16
        const float PI_F = 3.14159265358979323846f;
        if (tid <= 50) {
            int j = tid;
            float s = 0.f;
            for (int i = 0; i <= 50; i += 2) {          // odd i have W=0
                float w = (i == 0) ? 1.f : 2.f / (1.f - (float)(i * i));
                float l;
                if (j == 0 || j == 50) l = 0.5f;
                else { int r = (i * j) % 100; l = __cosf((float)r * (PI_F / 50.f)); }
                s += l * w;
            }
            cc[j]    = s * (2.f / 50.f);
            steps[j] = __cosf((float)j * (PI_F / 50.f));
        }
    } else {
        __shared__ float hs[16][15];
        __shared__ unsigned short a1s[16][264];   // bf16 relu(h@nw1.T+nb1), padded stride
        __shared__ float Pp[4 * 2 * 16];
        int b0 = (blk - 257) * 16, n = tid;
        if (tid < 240) { int bb = tid / 15, j = tid % 15; hs[bb][j] = h[(b0 + bb) * 15 + j]; }
        __syncthreads();
        float ir[16], nr[15];
        const float4* ip = (const float4*)(iw1 + n * 16);
        ((float4*)ir)[0] = ip[0]; ((float4*)ir)[1] = ip[1];
        ((float4*)ir)[2] = ip[2]; ((float4*)ir)[3] = ip[3];
        #pragma unroll
        for (int j = 0; j < 15; ++j) nr[j] = nw1[n * 15 + j];
        float bi = ib1[n], bn = nb1[n];
        #pragma unroll
        for (int bb = 0; bb < 16; ++bb) {
            float g = bi, a = bn;
            #pragma unroll
            for (int j = 0; j < 15; ++j) { float hv = hs[bb][j]; g += hv * ir[j + 1]; a += hv * nr[j]; }
            g1b[(b0 + bb) * 256 + n] = f2bf(g);
            a1s[bb][n] = f2bf(fmaxf(a, 0.f));
        }
        __syncthreads();

        // ---- nnet layer2 MFMA: A = a1s (16 batches x 256k), wave w owns 64 n ----
        int lane = tid & 63, w = tid >> 6, l16 = lane & 15, quad = lane >> 4;
        f32x4 acc[4];
        #pragma unroll
        for (int nt = 0; nt < 4; ++nt) acc[nt] = (f32x4){0.f, 0.f, 0.f, 0.f};
        #pragma unroll
        for (int ks = 0; ks < 8; ++ks) {
            bf16x8 af = *(const bf16x8*)&a1s[l16][ks * 32 + quad * 8];
            #pragma unroll
            for (int nt = 0; nt < 4; ++nt) {
                const float* np = nw2 + (w * 64 + nt * 16 + l16) * 256 + ks * 32 + quad * 8;
                float4 f0 = ((const float4*)np)[0];
                float4 f1 = ((const float4*)np)[1];
                union { uint4 u; bf16x8 v; } bf;
                bf.u.x = pk2bf(f0.x, f0.y); bf.u.y = pk2bf(f0.z, f0.w);
                bf.u.z = pk2bf(f1.x, f1.y); bf.u.w = pk2bf(f1.z, f1.w);
                acc[nt] = __builtin_amdgcn_mfma_f32_16x16x32_bf16(af, bf.v, acc[nt], 0, 0, 0);
            }
        }
        float p0[4], p1[4];
        #pragma unroll
        for (int i = 0; i < 4; ++i) { p0[i] = 0.f; p1[i] = 0.f; }
        #pragma unroll
        for (int nt = 0; nt < 4; ++nt) {
            int nn = w * 64 + nt * 16 + l16;
            float bias = nb2[nn], wa = nw3[nn], wb = nw3[256 + nn];
            #pragma unroll
            for (int i = 0; i < 4; ++i) {
                float v = acc[nt][i] + bias;
                v = v > 0.f ? v : 0.f;
                p0[i] += v * wa;
                p1[i] += v * wb;
            }
        }
        #pragma unroll
        for (int mask = 1; mask < 16; mask <<= 1)
            #pragma unroll
            for (int i = 0; i < 4; ++i) {
                p0[i] += __shfl_xor(p0[i], mask, 64);
                p1[i] += __shfl_xor(p1[i], mask, 64);
            }
        if (l16 == 0) {
            #pragma unroll
            for (int i = 0; i < 4; ++i) {
                int r = quad * 4 + i;                  // 0..15
                Pp[w * 32 + r]      = p0[i];
                Pp[w * 32 + 16 + r] = p1[i];
            }
        }
        __syncthreads();
        if (tid < 16) {
            float s0 = Pp[tid]      + Pp[32 + tid] + Pp[64 + tid] + Pp[96 + tid]  + nb3[0];
            float s1 = Pp[16 + tid] + Pp[48 + tid] + Pp[80 + tid] + Pp[112 + tid] + nb3[1];
            offs[b0 + tid] = s0;
            scal[b0 + tid] = __expf(s1);
        }
    }
}

// ---------------- k2: main integrand GEMM ----------------
// Block = 128 rows x 256 cols (FULL width, no hf split), K=256. 4 waves 2x2:
// mw = w&1 owns 64 rows, nw = w>>1 owns 128 cols. acc[4][8] = 128 accs ->
// __launch_bounds__(256,2): 256-VGPR budget, no spill (R5 measured 116 arch
// VGPRs for this compute shape; R7's spill was acc128 under (256,3)).
// LDS per wave-ks: B 8 + Ag 4 (bf16) + Wl 1 (bf16) = 13 b128 feeding 32 MFMA
// (R9 was 14 feeding 16) -> LDS-pipe floor ~26.5 us chip-wide.
// B streamed as four 32KB k-chunks (64 k x 256 cols), double-buffered DMA.
// g1/w1x staged as bf16 (2KB + 512B). K-loop: zero global accesses.
__launch_bounds__(256, 2)
__global__ void k2_main(const float* __restrict__ x, const unsigned short* __restrict__ g1b,
                        const unsigned short* __restrict__ w1xb, const unsigned short* __restrict__ iw2p,
                        const float* __restrict__ ib2, const float* __restrict__ iw3,
                        const float* __restrict__ ib3, const float* __restrict__ cc,
                        const float* __restrict__ steps, float* __restrict__ fvals) {
    __shared__ __align__(16) unsigned char smem[68608];
    // [0,65536): B dbuf 2 x 32KB, chunk layout [hh][c 0..7][n 0..127][8] bf16
    // [65536,67584): g1b rows blo..blo+3 (4 x 256 bf16)
    // [67584,68096): w1x bf16
    float* Pp = (float*)smem;     // epilogue alias: [128][36] f32 (18.4 KB)

    int tid = threadIdx.x;
    int m0  = blockIdx.x * 128;
    int lane = tid & 63, w = tid >> 6;
    int mw = w & 1, nw = w >> 1;
    int l16 = lane & 15, quad = lane >> 4;

    unsigned blo = (unsigned)(((unsigned long long)(unsigned)m0 * 657931ull) >> 25);  // m0/51

    int hh = tid >> 7, t7 = tid & 127;
    const unsigned char* bsrc = (const unsigned char*)iw2p + hh * 65536 + t7 * 16;
    unsigned char* bds0 = smem + hh * 16384 + t7 * 16;

    // DMA B chunk 0 (32KB: 2 halves x 16KB, 128 thr x 16B x 8 iters each)
    #pragma unroll
    for (int it = 0; it < 8; ++it)
        __builtin_amdgcn_global_load_lds(
            (const __attribute__((address_space(1))) unsigned int*)(bsrc + it * 2048),
            (__attribute__((address_space(3))) unsigned int*)(bds0 + it * 2048),
            16, 0, 0);
    // g1b rows (2KB) + w1x (512B)
    if (tid < 128)
        __builtin_amdgcn_global_load_lds(
            (const __attribute__((address_space(1))) unsigned int*)((const unsigned char*)g1b + blo * 512 + tid * 16),
            (__attribute__((address_space(3))) unsigned int*)(smem + 65536 + tid * 16),
            16, 0, 0);
    else if (tid < 160)
        __builtin_amdgcn_global_load_lds(
            (const __attribute__((address_space(1))) unsigned int*)((const unsigned char*)w1xb + (tid - 128) * 16),
            (__attribute__((address_space(3))) unsigned int*)(smem + 67584 + (tid - 128) * 16),
            16, 0, 0);

    // per-m-group row constants — overlaps with DMA
    float xs_[4]; int rel_[4];
    #pragma unroll
    for (int mt = 0; mt < 4; ++mt) {
        int m = m0 + mw * 64 + mt * 16 + l16;
        unsigned b = (unsigned)(((unsigned long long)(unsigned)m * 657931ull) >> 25);  // m/51
        int p = m - (int)b * 51;
        xs_[mt] = x[b] * (steps[p] + 1.f) * 0.5f;
        rel_[mt] = (int)(b - blo) * 256;
    }

    f32x4 acc[4][8];
    #pragma unroll
    for (int mt = 0; mt < 4; ++mt)
        #pragma unroll
        for (int nt = 0; nt < 8; ++nt)
            acc[mt][nt] = (f32x4){0.f, 0.f, 0.f, 0.f};

    const unsigned short* AgB = (const unsigned short*)(smem + 65536);
    const unsigned short* WlB = (const unsigned short*)(smem + 67584);

    #pragma unroll
    for (int kc = 0; kc < 4; ++kc) {
        __syncthreads();                       // DMA(kc) drained + all waves aligned
        if (kc < 3) {                          // prefetch next 32KB chunk into other buf
            const unsigned char* s2 = bsrc + (kc + 1) * 16384;
            unsigned char* d2 = smem + ((kc + 1) & 1) * 32768 + hh * 16384 + t7 * 16;
            #pragma unroll
            for (int it = 0; it < 8; ++it)
                __builtin_amdgcn_global_load_lds(
                    (const __attribute__((address_space(1))) unsigned int*)(s2 + it * 2048),
                    (__attribute__((address_space(3))) unsigned int*)(d2 + it * 2048),
                    16, 0, 0);
        }
        const unsigned short* Bl = (const unsigned short*)(smem + (kc & 1) * 32768) + nw * 8192;
        #pragma unroll
        for (int s = 0; s < 2; ++s) {
            int ks = kc * 2 + s;               // global 32-wide k-step 0..7
            int ko = ks * 32 + quad * 8;
            int cl = s * 4 + quad;             // chunk-local c 0..7

            // ---- unpack w1x slice (8 f32), shared across mt ----
            bf16x8 wv = *(const bf16x8*)(WlB + ko);
            float wl0 = (float)wv[0], wl1 = (float)wv[1], wl2 = (float)wv[2], wl3 = (float)wv[3];
            float wl4 = (float)wv[4], wl5 = (float)wv[5], wl6 = (float)wv[6], wl7 = (float)wv[7];

            // ---- A fragments for 4 m-groups (af = 16 VGPRs) ----
            union { uint4 u; bf16x8 v; } af[4];
            #pragma unroll
            for (int mt = 0; mt < 4; ++mt) {
                bf16x8 gv = *(const bf16x8*)(AgB + rel_[mt] + ko);
                float xs = xs_[mt];
                float a0 = fmaxf(fmaf(xs, wl0, (float)gv[0]), 0.f);
                float a1 = fmaxf(fmaf(xs, wl1, (float)gv[1]), 0.f);
                float a2 = fmaxf(fmaf(xs, wl2, (float)gv[2]), 0.f);
                float a3 = fmaxf(fmaf(xs, wl3, (float)gv[3]), 0.f);
                float a4 = fmaxf(fmaf(xs, wl4, (float)gv[4]), 0.f);
                float a5 = fmaxf(fmaf(xs, wl5, (float)gv[5]), 0.f);
                float a6 = fmaxf(fmaf(xs, wl6, (float)gv[6]), 0.f);
                float a7 = fmaxf(fmaf(xs, wl7, (float)gv[7]), 0.f);
                af[mt].u.x = pk2bf(a0, a1); af[mt].u.y = pk2bf(a2, a3);
                af[mt].u.z = pk2bf(a4, a5); af[mt].u.w = pk2bf(a6, a7);
            }

            // ---- B frags in two groups of 4 (bfr = 16 VGPRs live) ----
            #pragma unroll
            for (int g = 0; g < 2; ++g) {
                bf16x8 bfr[4];
                #pragma unroll
                for (int nt = 0; nt < 4; ++nt)
                    bfr[nt] = *(const bf16x8*)(Bl + cl * 1024 + ((g * 4 + nt) * 16 + l16) * 8);
                #pragma unroll
                for (int mt = 0; mt < 4; ++mt)
                    #pragma unroll
                    for (int nt = 0; nt < 4; ++nt)
                        acc[mt][g * 4 + nt] = __builtin_amdgcn_mfma_f32_16x16x32_bf16(
                            af[mt].v, bfr[nt], acc[mt][g * 4 + nt], 0, 0, 0);
            }
        }
    }

    // ---- epilogue: relu(+ib2), dot with iw3 over this wave's 128 cols ----
    float pf[4][4];
    #pragma unroll
    for (int mt = 0; mt < 4; ++mt)
        #pragma unroll
        for (int i = 0; i < 4; ++i) pf[mt][i] = 0.f;
    #pragma unroll
    for (int nt = 0; nt < 8; ++nt) {
        int n = nw * 128 + nt * 16 + l16;
        float bias = ib2[n], w3 = iw3[n];
        #pragma unroll
        for (int mt = 0; mt < 4; ++mt)
            #pragma unroll
            for (int i = 0; i < 4; ++i) {
                float v = acc[mt][nt][i] + bias;
                v = v > 0.f ? v : 0.f;
                pf[mt][i] += v * w3;
            }
    }
    __syncthreads();     // all LDS reads done; smem becomes Pp
    #pragma unroll
    for (int mt = 0; mt < 4; ++mt)
        #pragma unroll
        for (int i = 0; i < 4; ++i) {
            int row = mw * 64 + mt * 16 + quad * 4 + i;
            Pp[row * 36 + nw * 16 + l16] = pf[mt][i];
        }
    __syncthreads();
    if (tid < 128) {
        const float4* pp = (const float4*)(Pp + tid * 36);
        float4 v0 = pp[0], v1 = pp[1], v2 = pp[2], v3 = pp[3];
        float4 v4 = pp[4], v5 = pp[5], v6 = pp[6], v7 = pp[7];
        float s = v0.x + v0.y + v0.z + v0.w + v1.x + v1.y + v1.z + v1.w
                + v2.x + v2.y + v2.z + v2.w + v3.x + v3.y + v3.z + v3.w
                + v4.x + v4.y + v4.z + v4.w + v5.x + v5.y + v5.z + v5.w
                + v6.x + v6.y + v6.z + v6.w + v7.x + v7.y + v7.z + v7.w;
        s += ib3[0];
        int m = m0 + tid;
        unsigned b = (unsigned)(((unsigned long long)(unsigned)m * 657931ull) >> 25);
        int p = m - (int)b * 51;
        float f = s > 0.f ? s + 1.f : __expf(s);   // elu(s)+1
        fvals[m] = f * cc[p];
    }
}

// ---------------- k4: quadrature reduce + combine (wave per batch) ----------------
__global__ void k4_final(const float* __restrict__ x, const float* __restrict__ fvals,
                         const float* __restrict__ offs, const float* __restrict__ scal,
                         float* __restrict__ out) {
    int tid = threadIdx.x;
    int wv = tid >> 6, lane = tid & 63;
    int b = blockIdx.x * 4 + wv;
    float v = (lane < 51) ? fvals[b * 51 + lane] : 0.f;   // already (elu+1)*cc
    #pragma unroll
    for (int mask = 1; mask < 64; mask <<= 1) v += __shfl_xor(v, mask, 64);
    if (lane == 0)
        out[b] = scal[b] * (0.5f * x[b] * v) + offs[b];
}

extern "C" void kernel_launch(void* const* d_in, const int* in_sizes, int n_in,
                              void* d_out, int out_size, void* d_ws, size_t ws_size,
                              hipStream_t stream) {
    const float* x   = (const float*)d_in[0];
    const float* h   = (const float*)d_in[1];
    const float* iw1 = (const float*)d_in[2];
    const float* ib1 = (const float*)d_in[3];
    const float* iw2 = (const float*)d_in[4];
    const float* ib2 = (const float*)d_in[5];
    const float* iw3 = (const float*)d_in[6];
    const float* ib3 = (const float*)d_in[7];
    const float* nw1 = (const float*)d_in[8];
    const float* nb1 = (const float*)d_in[9];
    const float* nw2 = (const float*)d_in[10];
    const float* nb2 = (const float*)d_in[11];
    const float* nw3 = (const float*)d_in[12];
    const float* nb3 = (const float*)d_in[13];
    float* out = (float*)d_out;

    char* ws = (char*)d_ws;
    unsigned short* iw2p = (unsigned short*)(ws + OFF_IW2P);
    unsigned short* w1xb = (unsigned short*)(ws + OFF_W1XB);
    float* cc    = (float*)(ws + OFF_CC);
    float* steps = (float*)(ws + OFF_STEPS);
    float* offs  = (float*)(ws + OFF_OFFS);
    float* scal  = (float*)(ws + OFF_SCAL);
    unsigned short* g1b = (unsigned short*)(ws + OFF_G1B);
    float* fvals = (float*)(ws + OFF_FVALS);

    k1_fused<<<dim3(769), dim3(256), 0, stream>>>(iw2, nw1, iw1, ib1, nb1, h,
                                                  nw2, nb2, nw3, nb3,
                                                  iw2p, w1xb, cc, steps, g1b, offs, scal);
    k2_main<<<dim3(MTOT / 128), dim3(256), 0, stream>>>(x, g1b, w1xb, iw2p, ib2, iw3,
                                                        ib3, cc, steps, fvals);
    k4_final<<<dim3(BATCH / 4), dim3(256), 0, stream>>>(x, fvals, offs, scal, out);
}